// Round 4
// baseline (312.472 us; speedup 1.0000x reference)
//
#include <hip/hip_runtime.h>
#include <hip/hip_bf16.h>
#include <math.h>

#define S_LEN   2048
#define D_MODEL 1024
#define N_HEADS 16
#define HEAD_W  64
#define BATCH   2
#define MROWS   (BATCH * S_LEN)          // 4096
#define MASK_FILL -100000000.0f
#define LOG2E 1.4426950408889634f

typedef __attribute__((ext_vector_type(8))) short bf16x8;   // 8 bf16 = 4 VGPR
typedef __attribute__((ext_vector_type(4))) float f32x4;
typedef __attribute__((ext_vector_type(16))) float f32x16;
typedef unsigned short u16;
typedef unsigned int   u32;
typedef unsigned long long u64;

// raw v_exp_f32 (exp2); guarded for toolchain portability
__device__ __forceinline__ float fast_exp2(float x) {
#if __has_builtin(__builtin_amdgcn_exp2f)
    return __builtin_amdgcn_exp2f(x);
#else
    return __builtin_exp2f(x);
#endif
}

__device__ __forceinline__ float fast_rcp(float x) {
#if __has_builtin(__builtin_amdgcn_rcpf)
    return __builtin_amdgcn_rcpf(x);
#else
    return 1.0f / x;
#endif
}

// fp32 -> bf16 RNE (finite inputs only)
__device__ __forceinline__ u16 f2bf(float f) {
    u32 u = __float_as_uint(f);
    return (u16)((u + 0x7fffu + ((u >> 16) & 1u)) >> 16);
}

// pack 2 fp32 -> packed bf16x2 (RNE); lowers to v_cvt_pk_bf16_f32 on gfx950
__device__ __forceinline__ u32 pack_bf16x2(float lo, float hi) {
    __hip_bfloat162 t = __float22bfloat162_rn(make_float2(lo, hi));
    u32 r;
    __builtin_memcpy(&r, &t, 4);
    return r;
}

// async global->LDS, 16 B per lane; lp MUST be wave-uniform (HW: base + lane*16)
__device__ __forceinline__ void gld_lds16(const void* gp, void* lp) {
    __builtin_amdgcn_global_load_lds(
        (const __attribute__((address_space(1))) u32*)gp,
        (__attribute__((address_space(3))) u32*)lp, 16, 0, 0);
}

// p masked to 0 when the lane's bit in the wave-uniform word w is set.
// One VALU op: v_cndmask with SGPR-pair mask (bit l = lane l's element).
__device__ __forceinline__ float maskz(float p, u64 w) {
    float r;
    asm("v_cndmask_b32 %0, %1, 0, %2" : "=v"(r) : "v"(p), "s"(w));
    return r;
}

// ---------------------------------------------------------------------------
// Fused prep kernel. grid = (4096, 8):
//   y in [0,7): batched fp32 -> bf16 conversion jobs
//   y == 7, x < 2048: mask pack with per-block dtype detection.
// ---------------------------------------------------------------------------
struct CvtJobs {
    const float* src[7];
    u16* dst[7];
    int n[7];
};
__global__ __launch_bounds__(256) void prep_kernel(
    CvtJobs j, const unsigned char* __restrict__ mask, u64* __restrict__ bits) {
    const int t = blockIdx.y;
    if (t < 7) {
        const float* s = j.src[t];
        u16* d = j.dst[t];
        const int n = j.n[t];
        int i = (blockIdx.x * 256 + threadIdx.x) * 4;
        if (i < n) {
            float4 v = *(const float4*)(s + i);
            ushort4 o;
            o.x = f2bf(v.x); o.y = f2bf(v.y); o.z = f2bf(v.z); o.w = f2bf(v.w);
            *(ushort4*)(d + i) = o;
        }
        return;
    }
    if (blockIdx.x >= 2048) return;
    __shared__ int isByte;
    if (threadIdx.x == 0) isByte = 0;
    __syncthreads();
    const int e0 = blockIdx.x * 2048;
    const uint2 v = ((const uint2*)(mask + e0))[threadIdx.x];
    if (((v.x | v.y) & 0xFFFFFF00u) != 0u) isByte = 1;   // benign race
    __syncthreads();
    const int ib = isByte;
    const int* mi = (const int*)mask;
#pragma unroll
    for (int jj = 0; jj < 8; ++jj) {
        const int e = e0 + jj * 256 + threadIdx.x;
        const bool m = ib ? (mask[e] != 0) : (mi[e] != 0);
        const u64 bl = __ballot(m);
        if ((e & 63) == 0) bits[e >> 6] = bl;
    }
}

// ---------------------------------------------------------------------------
// Bit-transpose row-major mask words into 32x32-MFMA lane order:
// word[sg][c][T*16 + g*4 + q] bit l =
//   mask[sg*32 + (l&31)][c*64 + T*32 + q + 8*g + 4*(l>>5)]
// matching the st register layout (r = 4g+q: t = T*32 + (r&3)+8*(r>>2)+4*hi).
// grid = 64 blocks (sg = 32-row s-group), 256 thr; wave wv does c = wv*8..+7.
// ---------------------------------------------------------------------------
__global__ __launch_bounds__(256) void maskt_kernel(
    const u64* __restrict__ bits, u64* __restrict__ words) {
    const int tid = threadIdx.x, wv = tid >> 6, ln = tid & 63;
    const int l31 = ln & 31, hi = ln >> 5;
    const int sg = blockIdx.x;                 // 0..63
#pragma unroll
    for (int ci = 0; ci < 8; ++ci) {
        const int c = wv * 8 + ci;
        const u64 rw = bits[(size_t)(sg * 32 + l31) * 32 + c];
        u64 keep = 0;
#pragma unroll
        for (int k = 0; k < 32; ++k) {         // k = T*16 + g*4 + q
            const int T = k >> 4, g = (k >> 2) & 3, q = k & 3;
            const bool m = ((rw >> (T * 32 + q + 8 * g + 4 * hi)) & 1ull) != 0ull;
            const u64 bl = __ballot(m);
            if (ln == k) keep = bl;
        }
        if (ln < 32) words[((size_t)(sg * 32 + c) << 5) + ln] = keep;
    }
}

// ---------------------------------------------------------------------------
// bf16 MFMA GEMM core: C(128x128) = A(Mx1024) * Bt(1024x1024)^T
// ---------------------------------------------------------------------------
__device__ __forceinline__ void gemm_core_bf16(const u16* __restrict__ A,
                                               const u16* __restrict__ Bt,
                                               int m0, int n0, f32x4 acc[4][4]) {
    __shared__ u16 As[2][4096];   // [buf][chunk(4)][row(128)][8]
    __shared__ u16 Bs[2][4096];
    const int tid = threadIdx.x;
    const int wv = tid >> 6, ln = tid & 63;
    const int lane16 = ln & 15, quad = ln >> 4;
    const int wr = (wv >> 1) * 64, wc = (wv & 1) * 64;
    const u16* A0 = A + (size_t)(m0 + ln) * D_MODEL + wv * 8;
    const u16* A1 = A + (size_t)(m0 + 64 + ln) * D_MODEL + wv * 8;
    const u16* B0 = Bt + (size_t)(n0 + ln) * D_MODEL + wv * 8;
    const u16* B1 = Bt + (size_t)(n0 + 64 + ln) * D_MODEL + wv * 8;

    gld_lds16(A0, &As[0][wv * 1024]);
    gld_lds16(A1, &As[0][wv * 1024 + 512]);
    gld_lds16(B0, &Bs[0][wv * 1024]);
    gld_lds16(B1, &Bs[0][wv * 1024 + 512]);

    for (int kt = 0; kt < D_MODEL / 32; ++kt) {
        const int buf = kt & 1;
        __syncthreads();          // drains stage(kt); readers of buf^1 done
        if (kt < D_MODEL / 32 - 1) {
            const int ko = (kt + 1) * 32;
            gld_lds16(A0 + ko, &As[buf ^ 1][wv * 1024]);
            gld_lds16(A1 + ko, &As[buf ^ 1][wv * 1024 + 512]);
            gld_lds16(B0 + ko, &Bs[buf ^ 1][wv * 1024]);
            gld_lds16(B1 + ko, &Bs[buf ^ 1][wv * 1024 + 512]);
        }
        bf16x8 af[4], bfv[4];
#pragma unroll
        for (int mt = 0; mt < 4; ++mt)
            af[mt] = *(const bf16x8*)&As[buf][quad * 1024 + (wr + mt * 16 + lane16) * 8];
#pragma unroll
        for (int nt = 0; nt < 4; ++nt)
            bfv[nt] = *(const bf16x8*)&Bs[buf][quad * 1024 + (wc + nt * 16 + lane16) * 8];
#pragma unroll
        for (int mt = 0; mt < 4; ++mt)
#pragma unroll
            for (int nt = 0; nt < 4; ++nt)
                acc[mt][nt] = __builtin_amdgcn_mfma_f32_16x16x32_bf16(
                    af[mt], bfv[nt], acc[mt][nt], 0, 0, 0);
    }
}

// ---------------------------------------------------------------------------
// QKV projection. grid = (8, 32, 3).
// ---------------------------------------------------------------------------
__global__ __launch_bounds__(256, 4) void qkv_gemm_kernel(
    const u16* __restrict__ xq, const u16* __restrict__ xk, const u16* __restrict__ xv,
    const u16* __restrict__ wq, const u16* __restrict__ wk, const u16* __restrict__ wv,
    const float* __restrict__ bq, const float* __restrict__ bk, const float* __restrict__ bv,
    u16* __restrict__ qb, u16* __restrict__ kb, u16* __restrict__ vtmp) {
    const u16* A; const u16* Bt; const float* bias; u16* outp;
    const int z = blockIdx.z;
    if (z == 0)      { A = xq; Bt = wq; bias = bq; outp = qb; }
    else if (z == 1) { A = xk; Bt = wk; bias = bk; outp = kb; }
    else             { A = xv; Bt = wv; bias = bv; outp = vtmp; }
    f32x4 acc[4][4] = {};
    const int m0 = blockIdx.y * 128, n0 = blockIdx.x * 128;
    gemm_core_bf16(A, Bt, m0, n0, acc);

    const int tid = threadIdx.x;
    const int wvi = tid >> 6, ln = tid & 63;
    const int lane16 = ln & 15, quad = ln >> 4;
    const int wr = (wvi >> 1) * 64, wc = (wvi & 1) * 64;
    const float scale = (z == 0) ? LOG2E : 1.0f;
#pragma unroll
    for (int nt = 0; nt < 4; ++nt) {
        const int n = n0 + wc + nt * 16 + lane16;
        const float bb = bias[n];
        const int h = n >> 6, w = n & 63;
#pragma unroll
        for (int mt = 0; mt < 4; ++mt)
#pragma unroll
            for (int r = 0; r < 4; ++r) {
                const int m = m0 + wr + mt * 16 + quad * 4 + r;
                const int bidx = m >> 11, s = m & 2047;
                outp[((size_t)((bidx * N_HEADS + h) * S_LEN + s)) * HEAD_W + w] =
                    f2bf((acc[mt][nt][r] + bb) * scale);
            }
    }
}

// ---------------------------------------------------------------------------
// V transpose: (b,h,s,w) -> (b,h,w,t). grid = (32, 32), 256 threads.
// ---------------------------------------------------------------------------
__global__ __launch_bounds__(256) void vtrans_kernel(
    const u16* __restrict__ vtmp, u16* __restrict__ vbt) {
    __shared__ u16 T[64][72];
    const int tid = threadIdx.x;
    const int bh = blockIdx.y;
    const int s0 = blockIdx.x * 64;
    const int row = tid >> 2, seg = (tid & 3) * 16;
    const u16* src = vtmp + ((size_t)bh * S_LEN + s0 + row) * HEAD_W + seg;
    uint4 a = *(const uint4*)src;
    uint4 b2 = *(const uint4*)(src + 8);
    u16 tmp[16];
    *(uint4*)tmp = a; *(uint4*)(tmp + 8) = b2;
#pragma unroll
    for (int j = 0; j < 16; ++j) T[seg + j][row] = tmp[j];
    __syncthreads();
    u16* dst = vbt + ((size_t)bh * HEAD_W + row) * S_LEN + s0 + seg;
    *(uint4*)dst       = *(const uint4*)&T[row][seg];
    *(uint4*)(dst + 8) = *(const uint4*)&T[row][seg + 8];
}

// ---------------------------------------------------------------------------
// Output projection: out(4096x1024 fp32) = ab(bf16) * Wo^T + bo
// ---------------------------------------------------------------------------
__global__ __launch_bounds__(256, 4) void out_gemm_kernel(
    const u16* __restrict__ ab, const u16* __restrict__ wo,
    const float* __restrict__ bo, float* __restrict__ out) {
    f32x4 acc[4][4] = {};
    const int m0 = blockIdx.y * 128, n0 = blockIdx.x * 128;
    gemm_core_bf16(ab, wo, m0, n0, acc);
    const int tid = threadIdx.x;
    const int wvi = tid >> 6, ln = tid & 63;
    const int lane16 = ln & 15, quad = ln >> 4;
    const int wr = (wvi >> 1) * 64, wc = (wvi & 1) * 64;
#pragma unroll
    for (int nt = 0; nt < 4; ++nt) {
        const int n = n0 + wc + nt * 16 + lane16;
        const float bb = bo[n];
#pragma unroll
        for (int mt = 0; mt < 4; ++mt)
#pragma unroll
            for (int r = 0; r < 4; ++r) {
                const int m = m0 + wr + mt * 16 + quad * 4 + r;
                out[(size_t)m * D_MODEL + n] = acc[mt][nt][r] + bb;
            }
    }
}

// ---------------------------------------------------------------------------
// Flash attention half-pass, 32x32x16 bf16 MFMA. P transfer via per-wave Ps
// LDS buffer in absolute (s,t) coordinates (round-2-proven mechanism):
// store packed bf16 pairs from the verified C/D layout, read back contiguous
// 8-t A-frags (k = hi*8+j). grid = (16 s-tiles, 16 h, 4), XCD-swizzled.
// 256 thr = 4 waves, 32 q-rows/wave, 16 t-chunks of 64 per block.
// QK^T tile T: lane holds s = l&31 (col), t = T*32 + (r&3)+8*(r>>2)+4*hi.
// Row-sum l: per-lane f32 adds + one final shfl_xor(32).
// vs 16x16 version: MFMA issues per chunk 36 -> 16 (same FLOPs), no ones-MFMA.
// ---------------------------------------------------------------------------
__global__ __launch_bounds__(256, 3) void attn_kernel(
    const u16* __restrict__ qbuf, const u16* __restrict__ kbuf,
    const u16* __restrict__ vbt, const u64* __restrict__ maskw,
    float* __restrict__ Opart, float* __restrict__ lpart) {
    __shared__ u16 Ks[2][4096];       // [buf][i=w/8 (8)][t-row(64)][8]
    __shared__ u16 Vt[2][4096];       // [buf][i=t/8 (8)][w-row(64)][8]
    __shared__ u16 Ps[4][32 * 72];    // per-wave P[s(32)][t(64)], stride 72
    const int tid = threadIdx.x;
    const int wv = tid >> 6, ln = tid & 63;
    const int l31 = ln & 31, hi = ln >> 5;
    // bijective XCD-chunked swizzle: 1024 blocks = 8 XCDs x 128.
    const int fid = (blockIdx.z * N_HEADS + blockIdx.y) * (S_LEN / 128) + blockIdx.x;
    const int nid = (fid & 7) * 128 + (fid >> 3);
    const int s_blk = (nid & 15) * 128;
    const int rest = nid >> 4;                  // 0..63
    const int h = rest & 15;
    const int bz = rest >> 4;                   // 0..3
    const int b = bz >> 1, hf = bz & 1;
    const int c0 = hf * 16;                     // first t-chunk (of 32 total)
    const size_t hb = ((size_t)(b * N_HEADS + h)) * S_LEN * HEAD_W;
    const u16* Qg = qbuf + hb;
    const u16* Kg = kbuf + hb;
    const u16* Vg = vbt + hb;         // [w][t]
    const int sgw = (s_blk >> 5) + wv;          // 32-row s-group of this wave

    // Q B-frags from global, once: Q[s = base + l31][w = ks*16 + hi*8 + j]
    bf16x8 qa2[4];
#pragma unroll
    for (int ks = 0; ks < 4; ++ks)
        qa2[ks] = *(const bf16x8*)(Qg +
            (size_t)(s_blk + wv * 32 + l31) * HEAD_W + ks * 16 + hi * 8);

    {   // preload chunk c0 (chunk-major: instr i, rows = lanes)
        const int t0g = c0 * 64;
        const int i0 = 2 * wv, i1 = 2 * wv + 1;
        gld_lds16(Kg + (size_t)(t0g + ln) * HEAD_W + i0 * 8, &Ks[0][i0 * 512]);
        gld_lds16(Kg + (size_t)(t0g + ln) * HEAD_W + i1 * 8, &Ks[0][i1 * 512]);
        gld_lds16(Vg + (size_t)ln * S_LEN + t0g + i0 * 8, &Vt[0][i0 * 512]);
        gld_lds16(Vg + (size_t)ln * S_LEN + t0g + i1 * 8, &Vt[0][i1 * 512]);
    }

    f32x16 oacc2[2] = {};             // O[s(regs/hi)][w = W*32 + l31]
    float lsum = 0.0f;

    for (int ci = 0; ci < 16; ++ci) {
        const int c = c0 + ci;
        const int buf = ci & 1;
        __syncthreads();              // drains stage(ci); readers of buf^1 done
        if (ci < 15) {
            const int t1 = (c + 1) * 64;
            const int i0 = 2 * wv, i1 = 2 * wv + 1;
            gld_lds16(Kg + (size_t)(t1 + ln) * HEAD_W + i0 * 8, &Ks[buf ^ 1][i0 * 512]);
            gld_lds16(Kg + (size_t)(t1 + ln) * HEAD_W + i1 * 8, &Ks[buf ^ 1][i1 * 512]);
            gld_lds16(Vg + (size_t)ln * S_LEN + t1 + i0 * 8, &Vt[buf ^ 1][i0 * 512]);
            gld_lds16(Vg + (size_t)ln * S_LEN + t1 + i1 * 8, &Vt[buf ^ 1][i1 * 512]);
        }

        // QK^T + softmax numerator -> Ps (absolute (s,t) coords)
#pragma unroll
        for (int T = 0; T < 2; ++T) {          // two 32-row t-tiles per chunk
            f32x16 st = {};
#pragma unroll
            for (int ks = 0; ks < 4; ++ks) {
                const bf16x8 kf = *(const bf16x8*)&Ks[buf][
                    (ks * 2 + hi) * 512 + (T * 32 + l31) * 8];
                st = __builtin_amdgcn_mfma_f32_32x32x16_bf16(
                    kf, qa2[ks], st, 0, 0, 0);
            }
            const u64* __restrict__ wp = maskw +
                __builtin_amdgcn_readfirstlane(((sgw * 32 + c) << 5) + T * 16);
#pragma unroll
            for (int g = 0; g < 4; ++g) {
                const float p0 = maskz(fast_exp2(st[4 * g + 0]), wp[4 * g + 0]);
                const float p1 = maskz(fast_exp2(st[4 * g + 1]), wp[4 * g + 1]);
                const float p2 = maskz(fast_exp2(st[4 * g + 2]), wp[4 * g + 2]);
                const float p3 = maskz(fast_exp2(st[4 * g + 3]), wp[4 * g + 3]);
                lsum += (p0 + p1) + (p2 + p3);
                uint2 pk;
                pk.x = pack_bf16x2(p0, p1);    // t-cols +0,+1
                pk.y = pack_bf16x2(p2, p3);    // t-cols +2,+3
                // row s = l31, col base t = T*32 + 8g + 4hi
                *(uint2*)&Ps[wv][l31 * 72 + T * 32 + 8 * g + 4 * hi] = pk;
            }
        }

        // O += P·V (same-wave LDS round trip; waitcnt only, no barrier)
#pragma unroll
        for (int T = 0; T < 2; ++T)
#pragma unroll
            for (int gg = 0; gg < 2; ++gg) {
                // A-frag: P[s = l31][t = T*32 + gg*16 + hi*8 + j], j=0..7
                const bf16x8 pf = *(const bf16x8*)&Ps[wv][
                    l31 * 72 + T * 32 + gg * 16 + hi * 8];
#pragma unroll
                for (int W = 0; W < 2; ++W) {
                    const bf16x8 vf = *(const bf16x8*)&Vt[buf][
                        (T * 4 + gg * 2 + hi) * 512 + (W * 32 + l31) * 8];
                    oacc2[W] = __builtin_amdgcn_mfma_f32_32x32x16_bf16(
                        pf, vf, oacc2[W], 0, 0, 0);
                }
            }
    }

    // epilogue: fp32 partial O (rows b*2048+s, halves 4096 apart) + partial l
    float* OpB = Opart + ((size_t)(hf * 4096 + b * 2048)) * 1024;
#pragma unroll
    for (int W = 0; W < 2; ++W)
#pragma unroll
        for (int r = 0; r < 16; ++r) {
            const int s = s_blk + wv * 32 + (r & 3) + 8 * (r >> 2) + 4 * hi;
            OpB[(size_t)s * 1024 + h * 64 + W * 32 + l31] = oacc2[W][r];
        }
    lsum += __shfl_xor(lsum, 32);     // add the partner's t-half
    if (ln < 32) {
        const int srow = s_blk + wv * 32 + ln;
        lpart[(size_t)(hf * 4096 + b * 2048 + srow) * 16 + h] = lsum;
    }
}

// ---------------------------------------------------------------------------
// Combine halves: ab = (O1+O2) * 0.125/(l1+l2), bf16. grid = 4096 x 256 thr.
// ---------------------------------------------------------------------------
__global__ __launch_bounds__(256) void combine_kernel(
    const float* __restrict__ Op, const float* __restrict__ lp,
    u16* __restrict__ ab) {
    const int idx4 = blockIdx.x * 256 + threadIdx.x;
    const int row = idx4 >> 8;
    const int d = (idx4 & 255) * 4;
    const int h = d >> 6;
    const float l = lp[(size_t)row * 16 + h] + lp[(size_t)(4096 + row) * 16 + h];
    const float inv = 0.125f * fast_rcp(l);   // post-softmax 1/sqrt(64)
    float4 a = *(const float4*)(Op + (size_t)row * 1024 + d);
    float4 b = *(const float4*)(Op + (size_t)(4096 + row) * 1024 + d);
    ushort4 o;
    o.x = f2bf((a.x + b.x) * inv);
    o.y = f2bf((a.y + b.y) * inv);
    o.z = f2bf((a.z + b.z) * inv);
    o.w = f2bf((a.w + b.w) * inv);
    *(ushort4*)(ab + (size_t)row * 1024 + d) = o;
}

// ---------------------------------------------------------------------------
extern "C" void kernel_launch(void* const* d_in, const int* in_sizes, int n_in,
                              void* d_out, int out_size, void* d_ws, size_t ws_size,
                              hipStream_t stream) {
    const float* query = (const float*)d_in[0];
    const float* key   = (const float*)d_in[1];
    const float* value = (const float*)d_in[2];
    const void*  mask  = d_in[3];
    const float* Wq = (const float*)d_in[4];
    const float* bq = (const float*)d_in[5];
    const float* Wk = (const float*)d_in[6];
    const float* bk = (const float*)d_in[7];
    const float* Wv = (const float*)d_in[8];
    const float* bv = (const float*)d_in[9];
    const float* Wo = (const float*)d_in[10];
    const float* bo = (const float*)d_in[11];
    float* out = (float*)d_out;

    char* ws = (char*)d_ws;
    const size_t MB = 1024 * 1024;
    // persistent regions
    u64* bits  = (u64*)ws;                             // 512 KB (row-major)
    u64* maskt = (u64*)(ws + 512 * 1024);              // 512 KB (lane-word)
    u16* wob  = (u16*)(ws + 1 * MB);                   // 2 MB
    u16* qb   = (u16*)(ws + 3 * MB);                   // 8 MB (later: ab)
    u16* kb   = (u16*)(ws + 11 * MB);                  // 8 MB
    u16* vbt  = (u16*)(ws + 19 * MB);                  // 8 MB
    // unionA at +27 MB: phase1 = {xq,xk,xv,wqb,wkb,wvb,vtmp} (38 MB),
    //                   phase2 = {Opart 32 MB, lpart 512 KB}
    char* uA = ws + 27 * MB;
    u16* xq   = (u16*)(uA);
    u16* xk   = (u16*)(uA + 8 * MB);
    u16* xv   = (u16*)(uA + 16 * MB);
    u16* wqb  = (u16*)(uA + 24 * MB);
    u16* wkb  = (u16*)(uA + 26 * MB);
    u16* wvb  = (u16*)(uA + 28 * MB);
    u16* vtmp = (u16*)(uA + 30 * MB);
    float* Opart = (float*)(uA);                       // 32 MB (after qkv/vtrans)
    float* lpart = (float*)(uA + 32 * MB);             // 512 KB
    u16* ab = qb;                                      // qb dead after attn

    const size_t NACT = (size_t)MROWS * D_MODEL;       // 4M elements
    const size_t NW   = (size_t)D_MODEL * D_MODEL;     // 1M elements

    CvtJobs j;
    j.src[0] = query; j.dst[0] = xq;  j.n[0] = (int)NACT;
    j.src[1] = key;   j.dst[1] = xk;  j.n[1] = (int)NACT;
    j.src[2] = value; j.dst[2] = xv;  j.n[2] = (int)NACT;
    j.src[3] = Wq;    j.dst[3] = wqb; j.n[3] = (int)NW;
    j.src[4] = Wk;    j.dst[4] = wkb; j.n[4] = (int)NW;
    j.src[5] = Wv;    j.dst[5] = wvb; j.n[5] = (int)NW;
    j.src[6] = Wo;    j.dst[6] = wob; j.n[6] = (int)NW;
    prep_kernel<<<dim3(NACT / 1024, 8), 256, 0, stream>>>(
        j, (const unsigned char*)mask, bits);
    maskt_kernel<<<dim3(64), 256, 0, stream>>>(bits, maskt);

    qkv_gemm_kernel<<<dim3(D_MODEL / 128, MROWS / 128, 3), 256, 0, stream>>>(
        xq, xk, xv, wqb, wkb, wvb, bq, bk, bv, qb, kb, vtmp);
    vtrans_kernel<<<dim3(S_LEN / 64, BATCH * N_HEADS), 256, 0, stream>>>(vtmp, vbt);
    attn_kernel<<<dim3(S_LEN / 128, N_HEADS, BATCH * 2), 256, 0, stream>>>(
        qb, kb, vbt, maskt, Opart, lpart);
    combine_kernel<<<4096, 256, 0, stream>>>(Opart, lpart, ab);
    out_gemm_kernel<<<dim3(D_MODEL / 128, MROWS / 128), 256, 0, stream>>>(
        ab, wob, bo, out);
}

// Round 5
// 289.978 us; speedup vs baseline: 1.0776x; 1.0776x over previous
//
#include <hip/hip_runtime.h>
#include <hip/hip_bf16.h>
#include <math.h>

#define S_LEN   2048
#define D_MODEL 1024
#define N_HEADS 16
#define HEAD_W  64
#define BATCH   2
#define MROWS   (BATCH * S_LEN)          // 4096
#define MASK_FILL -100000000.0f
#define LOG2E 1.4426950408889634f

typedef __attribute__((ext_vector_type(8))) short bf16x8;   // 8 bf16 = 4 VGPR
typedef __attribute__((ext_vector_type(4))) float f32x4;
typedef __attribute__((ext_vector_type(16))) float f32x16;
typedef unsigned short u16;
typedef unsigned int   u32;
typedef unsigned long long u64;

// raw v_exp_f32 (exp2); guarded for toolchain portability
__device__ __forceinline__ float fast_exp2(float x) {
#if __has_builtin(__builtin_amdgcn_exp2f)
    return __builtin_amdgcn_exp2f(x);
#else
    return __builtin_exp2f(x);
#endif
}

__device__ __forceinline__ float fast_rcp(float x) {
#if __has_builtin(__builtin_amdgcn_rcpf)
    return __builtin_amdgcn_rcpf(x);
#else
    return 1.0f / x;
#endif
}

// fp32 -> bf16 RNE (finite inputs only)
__device__ __forceinline__ u16 f2bf(float f) {
    u32 u = __float_as_uint(f);
    return (u16)((u + 0x7fffu + ((u >> 16) & 1u)) >> 16);
}

// pack 2 fp32 -> packed bf16x2 (RNE); lowers to v_cvt_pk_bf16_f32 on gfx950
__device__ __forceinline__ u32 pack_bf16x2(float lo, float hi) {
    __hip_bfloat162 t = __float22bfloat162_rn(make_float2(lo, hi));
    u32 r;
    __builtin_memcpy(&r, &t, 4);
    return r;
}

// async global->LDS, 16 B per lane; lp MUST be wave-uniform (HW: base + lane*16)
__device__ __forceinline__ void gld_lds16(const void* gp, void* lp) {
    __builtin_amdgcn_global_load_lds(
        (const __attribute__((address_space(1))) u32*)gp,
        (__attribute__((address_space(3))) u32*)lp, 16, 0, 0);
}

// p masked to 0 when the lane's bit in the wave-uniform word w is set.
// One VALU op: v_cndmask with SGPR-pair mask (bit l = lane l's element).
__device__ __forceinline__ float maskz(float p, u64 w) {
    float r;
    asm("v_cndmask_b32 %0, %1, 0, %2" : "=v"(r) : "v"(p), "s"(w));
    return r;
}

// ---------------------------------------------------------------------------
// Fused prep kernel. grid = (4096, 8):
//   y in [0,7): batched fp32 -> bf16 conversion jobs
//   y == 7, x < 2048: mask pack with per-block dtype detection.
// ---------------------------------------------------------------------------
struct CvtJobs {
    const float* src[7];
    u16* dst[7];
    int n[7];
};
__global__ __launch_bounds__(256) void prep_kernel(
    CvtJobs j, const unsigned char* __restrict__ mask, u64* __restrict__ bits) {
    const int t = blockIdx.y;
    if (t < 7) {
        const float* s = j.src[t];
        u16* d = j.dst[t];
        const int n = j.n[t];
        int i = (blockIdx.x * 256 + threadIdx.x) * 4;
        if (i < n) {
            float4 v = *(const float4*)(s + i);
            ushort4 o;
            o.x = f2bf(v.x); o.y = f2bf(v.y); o.z = f2bf(v.z); o.w = f2bf(v.w);
            *(ushort4*)(d + i) = o;
        }
        return;
    }
    if (blockIdx.x >= 2048) return;
    __shared__ int isByte;
    if (threadIdx.x == 0) isByte = 0;
    __syncthreads();
    const int e0 = blockIdx.x * 2048;
    const uint2 v = ((const uint2*)(mask + e0))[threadIdx.x];
    if (((v.x | v.y) & 0xFFFFFF00u) != 0u) isByte = 1;   // benign race
    __syncthreads();
    const int ib = isByte;
    const int* mi = (const int*)mask;
#pragma unroll
    for (int jj = 0; jj < 8; ++jj) {
        const int e = e0 + jj * 256 + threadIdx.x;
        const bool m = ib ? (mask[e] != 0) : (mi[e] != 0);
        const u64 bl = __ballot(m);
        if ((e & 63) == 0) bits[e >> 6] = bl;
    }
}

// ---------------------------------------------------------------------------
// Bit-transpose row-major mask words into 32x32-MFMA lane order:
// word[sg][c][T*16 + g*4 + q] bit l =
//   mask[sg*32 + (l&31)][c*64 + T*32 + q + 8*g + 4*(l>>5)]
// grid = 64 blocks (sg = 32-row s-group), 256 thr; wave wv does c = wv*8..+7.
// ---------------------------------------------------------------------------
__global__ __launch_bounds__(256) void maskt_kernel(
    const u64* __restrict__ bits, u64* __restrict__ words) {
    const int tid = threadIdx.x, wv = tid >> 6, ln = tid & 63;
    const int l31 = ln & 31, hi = ln >> 5;
    const int sg = blockIdx.x;                 // 0..63
#pragma unroll
    for (int ci = 0; ci < 8; ++ci) {
        const int c = wv * 8 + ci;
        const u64 rw = bits[(size_t)(sg * 32 + l31) * 32 + c];
        u64 keep = 0;
#pragma unroll
        for (int k = 0; k < 32; ++k) {         // k = T*16 + g*4 + q
            const int T = k >> 4, g = (k >> 2) & 3, q = k & 3;
            const bool m = ((rw >> (T * 32 + q + 8 * g + 4 * hi)) & 1ull) != 0ull;
            const u64 bl = __ballot(m);
            if (ln == k) keep = bl;
        }
        if (ln < 32) words[((size_t)(sg * 32 + c) << 5) + ln] = keep;
    }
}

// ---------------------------------------------------------------------------
// bf16 MFMA GEMM core: C(128x128) = A(Mx1024) * Bt(1024x1024)^T
// ---------------------------------------------------------------------------
__device__ __forceinline__ void gemm_core_bf16(const u16* __restrict__ A,
                                               const u16* __restrict__ Bt,
                                               int m0, int n0, f32x4 acc[4][4]) {
    __shared__ u16 As[2][4096];   // [buf][chunk(4)][row(128)][8]
    __shared__ u16 Bs[2][4096];
    const int tid = threadIdx.x;
    const int wv = tid >> 6, ln = tid & 63;
    const int lane16 = ln & 15, quad = ln >> 4;
    const int wr = (wv >> 1) * 64, wc = (wv & 1) * 64;
    const u16* A0 = A + (size_t)(m0 + ln) * D_MODEL + wv * 8;
    const u16* A1 = A + (size_t)(m0 + 64 + ln) * D_MODEL + wv * 8;
    const u16* B0 = Bt + (size_t)(n0 + ln) * D_MODEL + wv * 8;
    const u16* B1 = Bt + (size_t)(n0 + 64 + ln) * D_MODEL + wv * 8;

    gld_lds16(A0, &As[0][wv * 1024]);
    gld_lds16(A1, &As[0][wv * 1024 + 512]);
    gld_lds16(B0, &Bs[0][wv * 1024]);
    gld_lds16(B1, &Bs[0][wv * 1024 + 512]);

    for (int kt = 0; kt < D_MODEL / 32; ++kt) {
        const int buf = kt & 1;
        __syncthreads();          // drains stage(kt); readers of buf^1 done
        if (kt < D_MODEL / 32 - 1) {
            const int ko = (kt + 1) * 32;
            gld_lds16(A0 + ko, &As[buf ^ 1][wv * 1024]);
            gld_lds16(A1 + ko, &As[buf ^ 1][wv * 1024 + 512]);
            gld_lds16(B0 + ko, &Bs[buf ^ 1][wv * 1024]);
            gld_lds16(B1 + ko, &Bs[buf ^ 1][wv * 1024 + 512]);
        }
        bf16x8 af[4], bfv[4];
#pragma unroll
        for (int mt = 0; mt < 4; ++mt)
            af[mt] = *(const bf16x8*)&As[buf][quad * 1024 + (wr + mt * 16 + lane16) * 8];
#pragma unroll
        for (int nt = 0; nt < 4; ++nt)
            bfv[nt] = *(const bf16x8*)&Bs[buf][quad * 1024 + (wc + nt * 16 + lane16) * 8];
#pragma unroll
        for (int mt = 0; mt < 4; ++mt)
#pragma unroll
            for (int nt = 0; nt < 4; ++nt)
                acc[mt][nt] = __builtin_amdgcn_mfma_f32_16x16x32_bf16(
                    af[mt], bfv[nt], acc[mt][nt], 0, 0, 0);
    }
}

// ---------------------------------------------------------------------------
// QKV projection. grid = (8, 32, 3).
// ---------------------------------------------------------------------------
__global__ __launch_bounds__(256, 4) void qkv_gemm_kernel(
    const u16* __restrict__ xq, const u16* __restrict__ xk, const u16* __restrict__ xv,
    const u16* __restrict__ wq, const u16* __restrict__ wk, const u16* __restrict__ wv,
    const float* __restrict__ bq, const float* __restrict__ bk, const float* __restrict__ bv,
    u16* __restrict__ qb, u16* __restrict__ kb, u16* __restrict__ vtmp) {
    const u16* A; const u16* Bt; const float* bias; u16* outp;
    const int z = blockIdx.z;
    if (z == 0)      { A = xq; Bt = wq; bias = bq; outp = qb; }
    else if (z == 1) { A = xk; Bt = wk; bias = bk; outp = kb; }
    else             { A = xv; Bt = wv; bias = bv; outp = vtmp; }
    f32x4 acc[4][4] = {};
    const int m0 = blockIdx.y * 128, n0 = blockIdx.x * 128;
    gemm_core_bf16(A, Bt, m0, n0, acc);

    const int tid = threadIdx.x;
    const int wvi = tid >> 6, ln = tid & 63;
    const int lane16 = ln & 15, quad = ln >> 4;
    const int wr = (wvi >> 1) * 64, wc = (wvi & 1) * 64;
    const float scale = (z == 0) ? LOG2E : 1.0f;
#pragma unroll
    for (int nt = 0; nt < 4; ++nt) {
        const int n = n0 + wc + nt * 16 + lane16;
        const float bb = bias[n];
        const int h = n >> 6, w = n & 63;
#pragma unroll
        for (int mt = 0; mt < 4; ++mt)
#pragma unroll
            for (int r = 0; r < 4; ++r) {
                const int m = m0 + wr + mt * 16 + quad * 4 + r;
                const int bidx = m >> 11, s = m & 2047;
                outp[((size_t)((bidx * N_HEADS + h) * S_LEN + s)) * HEAD_W + w] =
                    f2bf((acc[mt][nt][r] + bb) * scale);
            }
    }
}

// ---------------------------------------------------------------------------
// V transpose: (b,h,s,w) -> (b,h,w,t). grid = (32, 32), 256 threads.
// ---------------------------------------------------------------------------
__global__ __launch_bounds__(256) void vtrans_kernel(
    const u16* __restrict__ vtmp, u16* __restrict__ vbt) {
    __shared__ u16 T[64][72];
    const int tid = threadIdx.x;
    const int bh = blockIdx.y;
    const int s0 = blockIdx.x * 64;
    const int row = tid >> 2, seg = (tid & 3) * 16;
    const u16* src = vtmp + ((size_t)bh * S_LEN + s0 + row) * HEAD_W + seg;
    uint4 a = *(const uint4*)src;
    uint4 b2 = *(const uint4*)(src + 8);
    u16 tmp[16];
    *(uint4*)tmp = a; *(uint4*)(tmp + 8) = b2;
#pragma unroll
    for (int j = 0; j < 16; ++j) T[seg + j][row] = tmp[j];
    __syncthreads();
    u16* dst = vbt + ((size_t)bh * HEAD_W + row) * S_LEN + s0 + seg;
    *(uint4*)dst       = *(const uint4*)&T[row][seg];
    *(uint4*)(dst + 8) = *(const uint4*)&T[row][seg + 8];
}

// ---------------------------------------------------------------------------
// Output projection: out(4096x1024 fp32) = ab(bf16) * Wo^T + bo
// ---------------------------------------------------------------------------
__global__ __launch_bounds__(256, 4) void out_gemm_kernel(
    const u16* __restrict__ ab, const u16* __restrict__ wo,
    const float* __restrict__ bo, float* __restrict__ out) {
    f32x4 acc[4][4] = {};
    const int m0 = blockIdx.y * 128, n0 = blockIdx.x * 128;
    gemm_core_bf16(ab, wo, m0, n0, acc);
    const int tid = threadIdx.x;
    const int wvi = tid >> 6, ln = tid & 63;
    const int lane16 = ln & 15, quad = ln >> 4;
    const int wr = (wvi >> 1) * 64, wc = (wvi & 1) * 64;
#pragma unroll
    for (int nt = 0; nt < 4; ++nt) {
        const int n = n0 + wc + nt * 16 + lane16;
        const float bb = bo[n];
#pragma unroll
        for (int mt = 0; mt < 4; ++mt)
#pragma unroll
            for (int r = 0; r < 4; ++r) {
                const int m = m0 + wr + mt * 16 + quad * 4 + r;
                out[(size_t)m * D_MODEL + n] = acc[mt][nt][r] + bb;
            }
    }
}

// ---------------------------------------------------------------------------
// Flash attention half-pass, 32x32x16 bf16 MFMA, 8-wave blocks (512 thr),
// 256 s-rows per block -> grid (8 s-tiles, 16 h, 4 = b*2+hf) = 512 blocks
// = EXACTLY 2 blocks/CU, all resident, zero tail (round-4 was 3/CU + 25%
// tail at 1/CU). 16 waves/CU for latency hiding; K/V staging instrs per
// wave halved (16 gld_lds shared by 8 waves). All per-wave math/mechanisms
// byte-identical to the round-4-verified kernel (Ps LDS P-transfer in
// absolute (s,t) coords; 1-op scalar-word mask; raw v_exp).
// ---------------------------------------------------------------------------
__global__ __launch_bounds__(512, 4) void attn_kernel(
    const u16* __restrict__ qbuf, const u16* __restrict__ kbuf,
    const u16* __restrict__ vbt, const u64* __restrict__ maskw,
    float* __restrict__ Opart, float* __restrict__ lpart) {
    __shared__ u16 Ks[2][4096];       // [buf][i=w/8 (8)][t-row(64)][8]
    __shared__ u16 Vt[2][4096];       // [buf][i=t/8 (8)][w-row(64)][8]
    __shared__ u16 Ps[8][32 * 72];    // per-wave P[s(32)][t(64)], stride 72
    const int tid = threadIdx.x;
    const int wv = tid >> 6, ln = tid & 63;
    const int l31 = ln & 31, hi = ln >> 5;
    // bijective XCD-chunked swizzle (m204 form): 512 blocks = 8 XCDs x 64.
    // XCD x gets work [x*64, x*64+64) = 8 (b,h,hf) panel-halves x 8 s-tiles.
    const int lid = (blockIdx.z * N_HEADS + blockIdx.y) * 8 + blockIdx.x;
    const int nid = (lid & 7) * 64 + (lid >> 3);
    const int s_idx = nid & 7;
    const int G = nid >> 3;                     // 0..63
    const int h = G & 15;
    const int bz = G >> 4;                      // 0..3
    const int b = bz >> 1, hf = bz & 1;
    const int s_blk = s_idx * 256;
    const int c0 = hf * 16;                     // first t-chunk (of 32 total)
    const size_t hb = ((size_t)(b * N_HEADS + h)) * S_LEN * HEAD_W;
    const u16* Qg = qbuf + hb;
    const u16* Kg = kbuf + hb;
    const u16* Vg = vbt + hb;         // [w][t]
    const int sgw = (s_blk >> 5) + wv;          // 32-row s-group of this wave

    // Q B-frags from global, once: Q[s = base + l31][w = ks*16 + hi*8 + j]
    bf16x8 qa2[4];
#pragma unroll
    for (int ks = 0; ks < 4; ++ks)
        qa2[ks] = *(const bf16x8*)(Qg +
            (size_t)(s_blk + wv * 32 + l31) * HEAD_W + ks * 16 + hi * 8);

    {   // preload chunk c0 (chunk-major: instr i, rows = lanes); wave wv
        // stages K-slice i=wv and V-slice i=wv (8 waves cover i=0..7)
        const int t0g = c0 * 64;
        gld_lds16(Kg + (size_t)(t0g + ln) * HEAD_W + wv * 8, &Ks[0][wv * 512]);
        gld_lds16(Vg + (size_t)ln * S_LEN + t0g + wv * 8, &Vt[0][wv * 512]);
    }

    f32x16 oacc2[2] = {};             // O[s(regs/hi)][w = W*32 + l31]
    float lsum = 0.0f;

    for (int ci = 0; ci < 16; ++ci) {
        const int c = c0 + ci;
        const int buf = ci & 1;
        __syncthreads();              // drains stage(ci); readers of buf^1 done
        if (ci < 15) {
            const int t1 = (c + 1) * 64;
            gld_lds16(Kg + (size_t)(t1 + ln) * HEAD_W + wv * 8, &Ks[buf ^ 1][wv * 512]);
            gld_lds16(Vg + (size_t)ln * S_LEN + t1 + wv * 8, &Vt[buf ^ 1][wv * 512]);
        }

        // QK^T + softmax numerator -> Ps (absolute (s,t) coords)
#pragma unroll
        for (int T = 0; T < 2; ++T) {          // two 32-row t-tiles per chunk
            f32x16 st = {};
#pragma unroll
            for (int ks = 0; ks < 4; ++ks) {
                const bf16x8 kf = *(const bf16x8*)&Ks[buf][
                    (ks * 2 + hi) * 512 + (T * 32 + l31) * 8];
                st = __builtin_amdgcn_mfma_f32_32x32x16_bf16(
                    kf, qa2[ks], st, 0, 0, 0);
            }
            const u64* __restrict__ wp = maskw +
                __builtin_amdgcn_readfirstlane(((sgw * 32 + c) << 5) + T * 16);
#pragma unroll
            for (int g = 0; g < 4; ++g) {
                const float p0 = maskz(fast_exp2(st[4 * g + 0]), wp[4 * g + 0]);
                const float p1 = maskz(fast_exp2(st[4 * g + 1]), wp[4 * g + 1]);
                const float p2 = maskz(fast_exp2(st[4 * g + 2]), wp[4 * g + 2]);
                const float p3 = maskz(fast_exp2(st[4 * g + 3]), wp[4 * g + 3]);
                lsum += (p0 + p1) + (p2 + p3);
                uint2 pk;
                pk.x = pack_bf16x2(p0, p1);    // t-cols +0,+1
                pk.y = pack_bf16x2(p2, p3);    // t-cols +2,+3
                // row s = l31, col base t = T*32 + 8g + 4hi
                *(uint2*)&Ps[wv][l31 * 72 + T * 32 + 8 * g + 4 * hi] = pk;
            }
        }

        // O += P·V (same-wave LDS round trip; waitcnt only, no barrier)
#pragma unroll
        for (int T = 0; T < 2; ++T)
#pragma unroll
            for (int gg = 0; gg < 2; ++gg) {
                // A-frag: P[s = l31][t = T*32 + gg*16 + hi*8 + j], j=0..7
                const bf16x8 pf = *(const bf16x8*)&Ps[wv][
                    l31 * 72 + T * 32 + gg * 16 + hi * 8];
#pragma unroll
                for (int W = 0; W < 2; ++W) {
                    const bf16x8 vf = *(const bf16x8*)&Vt[buf][
                        (T * 4 + gg * 2 + hi) * 512 + (W * 32 + l31) * 8];
                    oacc2[W] = __builtin_amdgcn_mfma_f32_32x32x16_bf16(
                        pf, vf, oacc2[W], 0, 0, 0);
                }
            }
    }

    // epilogue: fp32 partial O (rows b*2048+s, halves 4096 apart) + partial l
    float* OpB = Opart + ((size_t)(hf * 4096 + b * 2048)) * 1024;
#pragma unroll
    for (int W = 0; W < 2; ++W)
#pragma unroll
        for (int r = 0; r < 16; ++r) {
            const int s = s_blk + wv * 32 + (r & 3) + 8 * (r >> 2) + 4 * hi;
            OpB[(size_t)s * 1024 + h * 64 + W * 32 + l31] = oacc2[W][r];
        }
    lsum += __shfl_xor(lsum, 32);     // add the partner's t-half
    if (ln < 32) {
        const int srow = s_blk + wv * 32 + ln;
        lpart[(size_t)(hf * 4096 + b * 2048 + srow) * 16 + h] = lsum;
    }
}

// ---------------------------------------------------------------------------
// Combine halves: ab = (O1+O2) * 0.125/(l1+l2), bf16. grid = 4096 x 256 thr.
// ---------------------------------------------------------------------------
__global__ __launch_bounds__(256) void combine_kernel(
    const float* __restrict__ Op, const float* __restrict__ lp,
    u16* __restrict__ ab) {
    const int idx4 = blockIdx.x * 256 + threadIdx.x;
    const int row = idx4 >> 8;
    const int d = (idx4 & 255) * 4;
    const int h = d >> 6;
    const float l = lp[(size_t)row * 16 + h] + lp[(size_t)(4096 + row) * 16 + h];
    const float inv = 0.125f * fast_rcp(l);   // post-softmax 1/sqrt(64)
    float4 a = *(const float4*)(Op + (size_t)row * 1024 + d);
    float4 b = *(const float4*)(Op + (size_t)(4096 + row) * 1024 + d);
    ushort4 o;
    o.x = f2bf((a.x + b.x) * inv);
    o.y = f2bf((a.y + b.y) * inv);
    o.z = f2bf((a.z + b.z) * inv);
    o.w = f2bf((a.w + b.w) * inv);
    *(ushort4*)(ab + (size_t)row * 1024 + d) = o;
}

// ---------------------------------------------------------------------------
extern "C" void kernel_launch(void* const* d_in, const int* in_sizes, int n_in,
                              void* d_out, int out_size, void* d_ws, size_t ws_size,
                              hipStream_t stream) {
    const float* query = (const float*)d_in[0];
    const float* key   = (const float*)d_in[1];
    const float* value = (const float*)d_in[2];
    const void*  mask  = d_in[3];
    const float* Wq = (const float*)d_in[4];
    const float* bq = (const float*)d_in[5];
    const float* Wk = (const float*)d_in[6];
    const float* bk = (const float*)d_in[7];
    const float* Wv = (const float*)d_in[8];
    const float* bv = (const float*)d_in[9];
    const float* Wo = (const float*)d_in[10];
    const float* bo = (const float*)d_in[11];
    float* out = (float*)d_out;

    char* ws = (char*)d_ws;
    const size_t MB = 1024 * 1024;
    // persistent regions
    u64* bits  = (u64*)ws;                             // 512 KB (row-major)
    u64* maskt = (u64*)(ws + 512 * 1024);              // 512 KB (lane-word)
    u16* wob  = (u16*)(ws + 1 * MB);                   // 2 MB
    u16* qb   = (u16*)(ws + 3 * MB);                   // 8 MB (later: ab)
    u16* kb   = (u16*)(ws + 11 * MB);                  // 8 MB
    u16* vbt  = (u16*)(ws + 19 * MB);                  // 8 MB
    // unionA at +27 MB: phase1 = {xq,xk,xv,wqb,wkb,wvb,vtmp} (38 MB),
    //                   phase2 = {Opart 32 MB, lpart 512 KB}
    char* uA = ws + 27 * MB;
    u16* xq   = (u16*)(uA);
    u16* xk   = (u16*)(uA + 8 * MB);
    u16* xv   = (u16*)(uA + 16 * MB);
    u16* wqb  = (u16*)(uA + 24 * MB);
    u16* wkb  = (u16*)(uA + 26 * MB);
    u16* wvb  = (u16*)(uA + 28 * MB);
    u16* vtmp = (u16*)(uA + 30 * MB);
    float* Opart = (float*)(uA);                       // 32 MB (after qkv/vtrans)
    float* lpart = (float*)(uA + 32 * MB);             // 512 KB
    u16* ab = qb;                                      // qb dead after attn

    const size_t NACT = (size_t)MROWS * D_MODEL;       // 4M elements
    const size_t NW   = (size_t)D_MODEL * D_MODEL;     // 1M elements

    CvtJobs j;
    j.src[0] = query; j.dst[0] = xq;  j.n[0] = (int)NACT;
    j.src[1] = key;   j.dst[1] = xk;  j.n[1] = (int)NACT;
    j.src[2] = value; j.dst[2] = xv;  j.n[2] = (int)NACT;
    j.src[3] = Wq;    j.dst[3] = wqb; j.n[3] = (int)NW;
    j.src[4] = Wk;    j.dst[4] = wkb; j.n[4] = (int)NW;
    j.src[5] = Wv;    j.dst[5] = wvb; j.n[5] = (int)NW;
    j.src[6] = Wo;    j.dst[6] = wob; j.n[6] = (int)NW;
    prep_kernel<<<dim3(NACT / 1024, 8), 256, 0, stream>>>(
        j, (const unsigned char*)mask, bits);
    maskt_kernel<<<dim3(64), 256, 0, stream>>>(bits, maskt);

    qkv_gemm_kernel<<<dim3(D_MODEL / 128, MROWS / 128, 3), 256, 0, stream>>>(
        xq, xk, xv, wqb, wkb, wvb, bq, bk, bv, qb, kb, vtmp);
    vtrans_kernel<<<dim3(S_LEN / 64, BATCH * N_HEADS), 256, 0, stream>>>(vtmp, vbt);
    attn_kernel<<<dim3(8, N_HEADS, 4), 512, 0, stream>>>(
        qb, kb, vbt, maskt, Opart, lpart);
    combine_kernel<<<4096, 256, 0, stream>>>(Opart, lpart, ab);
    out_gemm_kernel<<<dim3(D_MODEL / 128, MROWS / 128), 256, 0, stream>>>(
        ab, wob, bo, out);
}

// Round 6
// 286.831 us; speedup vs baseline: 1.0894x; 1.0110x over previous
//
#include <hip/hip_runtime.h>
#include <hip/hip_bf16.h>
#include <math.h>

#define S_LEN   2048
#define D_MODEL 1024
#define N_HEADS 16
#define HEAD_W  64
#define BATCH   2
#define MROWS   (BATCH * S_LEN)          // 4096
#define MASK_FILL -100000000.0f
#define LOG2E 1.4426950408889634f

typedef __attribute__((ext_vector_type(8))) short bf16x8;   // 8 bf16 = 4 VGPR
typedef __attribute__((ext_vector_type(4))) float f32x4;
typedef __attribute__((ext_vector_type(16))) float f32x16;
typedef unsigned short u16;
typedef unsigned int   u32;
typedef unsigned long long u64;

// raw v_exp_f32 (exp2); guarded for toolchain portability
__device__ __forceinline__ float fast_exp2(float x) {
#if __has_builtin(__builtin_amdgcn_exp2f)
    return __builtin_amdgcn_exp2f(x);
#else
    return __builtin_exp2f(x);
#endif
}

__device__ __forceinline__ float fast_rcp(float x) {
#if __has_builtin(__builtin_amdgcn_rcpf)
    return __builtin_amdgcn_rcpf(x);
#else
    return 1.0f / x;
#endif
}

// fp32 -> bf16 RNE (finite inputs only)
__device__ __forceinline__ u16 f2bf(float f) {
    u32 u = __float_as_uint(f);
    return (u16)((u + 0x7fffu + ((u >> 16) & 1u)) >> 16);
}

// pack 2 fp32 -> packed bf16x2 (RNE); lowers to v_cvt_pk_bf16_f32 on gfx950
__device__ __forceinline__ u32 pack_bf16x2(float lo, float hi) {
    __hip_bfloat162 t = __float22bfloat162_rn(make_float2(lo, hi));
    u32 r;
    __builtin_memcpy(&r, &t, 4);
    return r;
}

// async global->LDS, 16 B per lane; lp MUST be wave-uniform (HW: base + lane*16)
__device__ __forceinline__ void gld_lds16(const void* gp, void* lp) {
    __builtin_amdgcn_global_load_lds(
        (const __attribute__((address_space(1))) u32*)gp,
        (__attribute__((address_space(3))) u32*)lp, 16, 0, 0);
}

// p masked to 0 when the lane's bit in the wave-uniform word w is set.
// One VALU op: v_cndmask with SGPR-pair mask (bit l = lane l's element).
__device__ __forceinline__ float maskz(float p, u64 w) {
    float r;
    asm("v_cndmask_b32 %0, %1, 0, %2" : "=v"(r) : "v"(p), "s"(w));
    return r;
}

// ---------------------------------------------------------------------------
// Fused prep kernel. grid = (4096, 8):
//   y in [0,7): batched fp32 -> bf16 conversion jobs
//   y == 7, x < 2048: mask pack with per-block dtype detection.
// ---------------------------------------------------------------------------
struct CvtJobs {
    const float* src[7];
    u16* dst[7];
    int n[7];
};
__global__ __launch_bounds__(256) void prep_kernel(
    CvtJobs j, const unsigned char* __restrict__ mask, u64* __restrict__ bits) {
    const int t = blockIdx.y;
    if (t < 7) {
        const float* s = j.src[t];
        u16* d = j.dst[t];
        const int n = j.n[t];
        int i = (blockIdx.x * 256 + threadIdx.x) * 4;
        if (i < n) {
            float4 v = *(const float4*)(s + i);
            ushort4 o;
            o.x = f2bf(v.x); o.y = f2bf(v.y); o.z = f2bf(v.z); o.w = f2bf(v.w);
            *(ushort4*)(d + i) = o;
        }
        return;
    }
    if (blockIdx.x >= 2048) return;
    __shared__ int isByte;
    if (threadIdx.x == 0) isByte = 0;
    __syncthreads();
    const int e0 = blockIdx.x * 2048;
    const uint2 v = ((const uint2*)(mask + e0))[threadIdx.x];
    if (((v.x | v.y) & 0xFFFFFF00u) != 0u) isByte = 1;   // benign race
    __syncthreads();
    const int ib = isByte;
    const int* mi = (const int*)mask;
#pragma unroll
    for (int jj = 0; jj < 8; ++jj) {
        const int e = e0 + jj * 256 + threadIdx.x;
        const bool m = ib ? (mask[e] != 0) : (mi[e] != 0);
        const u64 bl = __ballot(m);
        if ((e & 63) == 0) bits[e >> 6] = bl;
    }
}

// ---------------------------------------------------------------------------
// Bit-transpose row-major mask words into 32x32-MFMA lane order:
// word[sg][c][T*16 + g*4 + q] bit l =
//   mask[sg*32 + (l&31)][c*64 + T*32 + q + 8*g + 4*(l>>5)]
// grid = 64 blocks (sg = 32-row s-group), 256 thr; wave wv does c = wv*8..+7.
// ---------------------------------------------------------------------------
__global__ __launch_bounds__(256) void maskt_kernel(
    const u64* __restrict__ bits, u64* __restrict__ words) {
    const int tid = threadIdx.x, wv = tid >> 6, ln = tid & 63;
    const int l31 = ln & 31, hi = ln >> 5;
    const int sg = blockIdx.x;                 // 0..63
#pragma unroll
    for (int ci = 0; ci < 8; ++ci) {
        const int c = wv * 8 + ci;
        const u64 rw = bits[(size_t)(sg * 32 + l31) * 32 + c];
        u64 keep = 0;
#pragma unroll
        for (int k = 0; k < 32; ++k) {         // k = T*16 + g*4 + q
            const int T = k >> 4, g = (k >> 2) & 3, q = k & 3;
            const bool m = ((rw >> (T * 32 + q + 8 * g + 4 * hi)) & 1ull) != 0ull;
            const u64 bl = __ballot(m);
            if (ln == k) keep = bl;
        }
        if (ln < 32) words[((size_t)(sg * 32 + c) << 5) + ln] = keep;
    }
}

// ---------------------------------------------------------------------------
// bf16 MFMA GEMM core: C(128x128) = A(Mx1024) * Bt(1024x1024)^T
// ---------------------------------------------------------------------------
__device__ __forceinline__ void gemm_core_bf16(const u16* __restrict__ A,
                                               const u16* __restrict__ Bt,
                                               int m0, int n0, f32x4 acc[4][4]) {
    __shared__ u16 As[2][4096];   // [buf][chunk(4)][row(128)][8]
    __shared__ u16 Bs[2][4096];
    const int tid = threadIdx.x;
    const int wv = tid >> 6, ln = tid & 63;
    const int lane16 = ln & 15, quad = ln >> 4;
    const int wr = (wv >> 1) * 64, wc = (wv & 1) * 64;
    const u16* A0 = A + (size_t)(m0 + ln) * D_MODEL + wv * 8;
    const u16* A1 = A + (size_t)(m0 + 64 + ln) * D_MODEL + wv * 8;
    const u16* B0 = Bt + (size_t)(n0 + ln) * D_MODEL + wv * 8;
    const u16* B1 = Bt + (size_t)(n0 + 64 + ln) * D_MODEL + wv * 8;

    gld_lds16(A0, &As[0][wv * 1024]);
    gld_lds16(A1, &As[0][wv * 1024 + 512]);
    gld_lds16(B0, &Bs[0][wv * 1024]);
    gld_lds16(B1, &Bs[0][wv * 1024 + 512]);

    for (int kt = 0; kt < D_MODEL / 32; ++kt) {
        const int buf = kt & 1;
        __syncthreads();          // drains stage(kt); readers of buf^1 done
        if (kt < D_MODEL / 32 - 1) {
            const int ko = (kt + 1) * 32;
            gld_lds16(A0 + ko, &As[buf ^ 1][wv * 1024]);
            gld_lds16(A1 + ko, &As[buf ^ 1][wv * 1024 + 512]);
            gld_lds16(B0 + ko, &Bs[buf ^ 1][wv * 1024]);
            gld_lds16(B1 + ko, &Bs[buf ^ 1][wv * 1024 + 512]);
        }
        bf16x8 af[4], bfv[4];
#pragma unroll
        for (int mt = 0; mt < 4; ++mt)
            af[mt] = *(const bf16x8*)&As[buf][quad * 1024 + (wr + mt * 16 + lane16) * 8];
#pragma unroll
        for (int nt = 0; nt < 4; ++nt)
            bfv[nt] = *(const bf16x8*)&Bs[buf][quad * 1024 + (wc + nt * 16 + lane16) * 8];
#pragma unroll
        for (int mt = 0; mt < 4; ++mt)
#pragma unroll
            for (int nt = 0; nt < 4; ++nt)
                acc[mt][nt] = __builtin_amdgcn_mfma_f32_16x16x32_bf16(
                    af[mt], bfv[nt], acc[mt][nt], 0, 0, 0);
    }
}

// ---------------------------------------------------------------------------
// QKV projection. grid = (8, 32, 3), XCD-chunk-remapped: dispatch-linear id
// d has n fastest -> default XCD = n means every XCD streams ALL of A (A
// fetched ~8x; measured 101 MB vs 30 MB ideal). Remap w = (d&7)*96 + (d>>3)
// gives XCD x a contiguous 96-block chunk (~12 m-tiles x all 8 n of one z):
// per-XCD L2 set = A 3MB + B 2-4MB; A fetched once total.
// ---------------------------------------------------------------------------
__global__ __launch_bounds__(256, 4) void qkv_gemm_kernel(
    const u16* __restrict__ xq, const u16* __restrict__ xk, const u16* __restrict__ xv,
    const u16* __restrict__ wq, const u16* __restrict__ wk, const u16* __restrict__ wv,
    const float* __restrict__ bq, const float* __restrict__ bk, const float* __restrict__ bv,
    u16* __restrict__ qb, u16* __restrict__ kb, u16* __restrict__ vtmp) {
    const int d = (blockIdx.z * 32 + blockIdx.y) * 8 + blockIdx.x;
    const int w0 = (d & 7) * 96 + (d >> 3);    // bijective: d = (w0%96)*8 + w0/96
    const int z = w0 >> 8;                     // 0..2
    const int rem = w0 & 255;
    const int m0 = (rem >> 3) * 128, n0 = (rem & 7) * 128;
    const u16* A; const u16* Bt; const float* bias; u16* outp;
    if (z == 0)      { A = xq; Bt = wq; bias = bq; outp = qb; }
    else if (z == 1) { A = xk; Bt = wk; bias = bk; outp = kb; }
    else             { A = xv; Bt = wv; bias = bv; outp = vtmp; }
    f32x4 acc[4][4] = {};
    gemm_core_bf16(A, Bt, m0, n0, acc);

    const int tid = threadIdx.x;
    const int wvi = tid >> 6, ln = tid & 63;
    const int lane16 = ln & 15, quad = ln >> 4;
    const int wr = (wvi >> 1) * 64, wc = (wvi & 1) * 64;
    const float scale = (z == 0) ? LOG2E : 1.0f;
#pragma unroll
    for (int nt = 0; nt < 4; ++nt) {
        const int n = n0 + wc + nt * 16 + lane16;
        const float bb = bias[n];
        const int h = n >> 6, w = n & 63;
#pragma unroll
        for (int mt = 0; mt < 4; ++mt)
#pragma unroll
            for (int r = 0; r < 4; ++r) {
                const int m = m0 + wr + mt * 16 + quad * 4 + r;
                const int bidx = m >> 11, s = m & 2047;
                outp[((size_t)((bidx * N_HEADS + h) * S_LEN + s)) * HEAD_W + w] =
                    f2bf((acc[mt][nt][r] + bb) * scale);
            }
    }
}

// ---------------------------------------------------------------------------
// V transpose: (b,h,s,w) -> (b,h,w,t). grid = (32, 32), 256 threads.
// ---------------------------------------------------------------------------
__global__ __launch_bounds__(256) void vtrans_kernel(
    const u16* __restrict__ vtmp, u16* __restrict__ vbt) {
    __shared__ u16 T[64][72];
    const int tid = threadIdx.x;
    const int bh = blockIdx.y;
    const int s0 = blockIdx.x * 64;
    const int row = tid >> 2, seg = (tid & 3) * 16;
    const u16* src = vtmp + ((size_t)bh * S_LEN + s0 + row) * HEAD_W + seg;
    uint4 a = *(const uint4*)src;
    uint4 b2 = *(const uint4*)(src + 8);
    u16 tmp[16];
    *(uint4*)tmp = a; *(uint4*)(tmp + 8) = b2;
#pragma unroll
    for (int j = 0; j < 16; ++j) T[seg + j][row] = tmp[j];
    __syncthreads();
    u16* dst = vbt + ((size_t)bh * HEAD_W + row) * S_LEN + s0 + seg;
    *(uint4*)dst       = *(const uint4*)&T[row][seg];
    *(uint4*)(dst + 8) = *(const uint4*)&T[row][seg + 8];
}

// ---------------------------------------------------------------------------
// Output projection: out(4096x1024 fp32) = ab(bf16) * Wo^T + bo.
// grid (8,32), XCD-chunk-remapped (w = (d&7)*32 + d>>3): per-XCD set =
// 4 m-tiles (1MB ab) + full wob (2MB) = 3MB, fits 4MB L2.
// ---------------------------------------------------------------------------
__global__ __launch_bounds__(256, 4) void out_gemm_kernel(
    const u16* __restrict__ ab, const u16* __restrict__ wo,
    const float* __restrict__ bo, float* __restrict__ out) {
    const int d = blockIdx.y * 8 + blockIdx.x;
    const int w0 = (d & 7) * 32 + (d >> 3);    // bijective on [0,256)
    const int m0 = (w0 >> 3) * 128, n0 = (w0 & 7) * 128;
    f32x4 acc[4][4] = {};
    gemm_core_bf16(ab, wo, m0, n0, acc);
    const int tid = threadIdx.x;
    const int wvi = tid >> 6, ln = tid & 63;
    const int lane16 = ln & 15, quad = ln >> 4;
    const int wr = (wvi >> 1) * 64, wc = (wvi & 1) * 64;
#pragma unroll
    for (int nt = 0; nt < 4; ++nt) {
        const int n = n0 + wc + nt * 16 + lane16;
        const float bb = bo[n];
#pragma unroll
        for (int mt = 0; mt < 4; ++mt)
#pragma unroll
            for (int r = 0; r < 4; ++r) {
                const int m = m0 + wr + mt * 16 + quad * 4 + r;
                out[(size_t)m * D_MODEL + n] = acc[mt][nt][r] + bb;
            }
    }
}

// ---------------------------------------------------------------------------
// Flash attention half-pass, 32x32x16 bf16 MFMA, 8-wave blocks (512 thr),
// 256 s-rows per block -> grid (8 s-tiles, 16 h, 4 = b*2+hf) = 512 blocks
// = EXACTLY 2 blocks/CU, all resident, zero tail. 16 waves/CU for latency
// hiding; K/V staging instrs per wave = 2 (shared across 8 waves).
// Ps LDS P-transfer in absolute (s,t) coords; 1-op scalar-word mask;
// raw v_exp; per-lane row-sum + final shfl_xor(32).
// ---------------------------------------------------------------------------
__global__ __launch_bounds__(512, 4) void attn_kernel(
    const u16* __restrict__ qbuf, const u16* __restrict__ kbuf,
    const u16* __restrict__ vbt, const u64* __restrict__ maskw,
    float* __restrict__ Opart, float* __restrict__ lpart) {
    __shared__ u16 Ks[2][4096];       // [buf][i=w/8 (8)][t-row(64)][8]
    __shared__ u16 Vt[2][4096];       // [buf][i=t/8 (8)][w-row(64)][8]
    __shared__ u16 Ps[8][32 * 72];    // per-wave P[s(32)][t(64)], stride 72
    const int tid = threadIdx.x;
    const int wv = tid >> 6, ln = tid & 63;
    const int l31 = ln & 31, hi = ln >> 5;
    // bijective XCD-chunked swizzle: 512 blocks = 8 XCDs x 64.
    const int lid = (blockIdx.z * N_HEADS + blockIdx.y) * 8 + blockIdx.x;
    const int nid = (lid & 7) * 64 + (lid >> 3);
    const int s_idx = nid & 7;
    const int G = nid >> 3;                     // 0..63
    const int h = G & 15;
    const int bz = G >> 4;                      // 0..3
    const int b = bz >> 1, hf = bz & 1;
    const int s_blk = s_idx * 256;
    const int c0 = hf * 16;                     // first t-chunk (of 32 total)
    const size_t hb = ((size_t)(b * N_HEADS + h)) * S_LEN * HEAD_W;
    const u16* Qg = qbuf + hb;
    const u16* Kg = kbuf + hb;
    const u16* Vg = vbt + hb;         // [w][t]
    const int sgw = (s_blk >> 5) + wv;          // 32-row s-group of this wave

    // Q B-frags from global, once: Q[s = base + l31][w = ks*16 + hi*8 + j]
    bf16x8 qa2[4];
#pragma unroll
    for (int ks = 0; ks < 4; ++ks)
        qa2[ks] = *(const bf16x8*)(Qg +
            (size_t)(s_blk + wv * 32 + l31) * HEAD_W + ks * 16 + hi * 8);

    {   // preload chunk c0; wave wv stages K-slice and V-slice i=wv
        const int t0g = c0 * 64;
        gld_lds16(Kg + (size_t)(t0g + ln) * HEAD_W + wv * 8, &Ks[0][wv * 512]);
        gld_lds16(Vg + (size_t)ln * S_LEN + t0g + wv * 8, &Vt[0][wv * 512]);
    }

    f32x16 oacc2[2] = {};             // O[s(regs/hi)][w = W*32 + l31]
    float lsum = 0.0f;

    for (int ci = 0; ci < 16; ++ci) {
        const int c = c0 + ci;
        const int buf = ci & 1;
        __syncthreads();              // drains stage(ci); readers of buf^1 done
        if (ci < 15) {
            const int t1 = (c + 1) * 64;
            gld_lds16(Kg + (size_t)(t1 + ln) * HEAD_W + wv * 8, &Ks[buf ^ 1][wv * 512]);
            gld_lds16(Vg + (size_t)ln * S_LEN + t1 + wv * 8, &Vt[buf ^ 1][wv * 512]);
        }

        // QK^T + softmax numerator -> Ps (absolute (s,t) coords)
#pragma unroll
        for (int T = 0; T < 2; ++T) {          // two 32-row t-tiles per chunk
            f32x16 st = {};
#pragma unroll
            for (int ks = 0; ks < 4; ++ks) {
                const bf16x8 kf = *(const bf16x8*)&Ks[buf][
                    (ks * 2 + hi) * 512 + (T * 32 + l31) * 8];
                st = __builtin_amdgcn_mfma_f32_32x32x16_bf16(
                    kf, qa2[ks], st, 0, 0, 0);
            }
            const u64* __restrict__ wp = maskw +
                __builtin_amdgcn_readfirstlane(((sgw * 32 + c) << 5) + T * 16);
#pragma unroll
            for (int g = 0; g < 4; ++g) {
                const float p0 = maskz(fast_exp2(st[4 * g + 0]), wp[4 * g + 0]);
                const float p1 = maskz(fast_exp2(st[4 * g + 1]), wp[4 * g + 1]);
                const float p2 = maskz(fast_exp2(st[4 * g + 2]), wp[4 * g + 2]);
                const float p3 = maskz(fast_exp2(st[4 * g + 3]), wp[4 * g + 3]);
                lsum += (p0 + p1) + (p2 + p3);
                uint2 pk;
                pk.x = pack_bf16x2(p0, p1);    // t-cols +0,+1
                pk.y = pack_bf16x2(p2, p3);    // t-cols +2,+3
                // row s = l31, col base t = T*32 + 8g + 4hi
                *(uint2*)&Ps[wv][l31 * 72 + T * 32 + 8 * g + 4 * hi] = pk;
            }
        }

        // O += P·V (same-wave LDS round trip; waitcnt only, no barrier)
#pragma unroll
        for (int T = 0; T < 2; ++T)
#pragma unroll
            for (int gg = 0; gg < 2; ++gg) {
                // A-frag: P[s = l31][t = T*32 + gg*16 + hi*8 + j], j=0..7
                const bf16x8 pf = *(const bf16x8*)&Ps[wv][
                    l31 * 72 + T * 32 + gg * 16 + hi * 8];
#pragma unroll
                for (int W = 0; W < 2; ++W) {
                    const bf16x8 vf = *(const bf16x8*)&Vt[buf][
                        (T * 4 + gg * 2 + hi) * 512 + (W * 32 + l31) * 8];
                    oacc2[W] = __builtin_amdgcn_mfma_f32_32x32x16_bf16(
                        pf, vf, oacc2[W], 0, 0, 0);
                }
            }
    }

    // epilogue: fp32 partial O (rows b*2048+s, halves 4096 apart) + partial l
    float* OpB = Opart + ((size_t)(hf * 4096 + b * 2048)) * 1024;
#pragma unroll
    for (int W = 0; W < 2; ++W)
#pragma unroll
        for (int r = 0; r < 16; ++r) {
            const int s = s_blk + wv * 32 + (r & 3) + 8 * (r >> 2) + 4 * hi;
            OpB[(size_t)s * 1024 + h * 64 + W * 32 + l31] = oacc2[W][r];
        }
    lsum += __shfl_xor(lsum, 32);     // add the partner's t-half
    if (ln < 32) {
        const int srow = s_blk + wv * 32 + ln;
        lpart[(size_t)(hf * 4096 + b * 2048 + srow) * 16 + h] = lsum;
    }
}

// ---------------------------------------------------------------------------
// Combine halves: ab = (O1+O2) * 0.125/(l1+l2), bf16. grid = 4096 x 256 thr.
// ---------------------------------------------------------------------------
__global__ __launch_bounds__(256) void combine_kernel(
    const float* __restrict__ Op, const float* __restrict__ lp,
    u16* __restrict__ ab) {
    const int idx4 = blockIdx.x * 256 + threadIdx.x;
    const int row = idx4 >> 8;
    const int d = (idx4 & 255) * 4;
    const int h = d >> 6;
    const float l = lp[(size_t)row * 16 + h] + lp[(size_t)(4096 + row) * 16 + h];
    const float inv = 0.125f * fast_rcp(l);   // post-softmax 1/sqrt(64)
    float4 a = *(const float4*)(Op + (size_t)row * 1024 + d);
    float4 b = *(const float4*)(Op + (size_t)(4096 + row) * 1024 + d);
    ushort4 o;
    o.x = f2bf((a.x + b.x) * inv);
    o.y = f2bf((a.y + b.y) * inv);
    o.z = f2bf((a.z + b.z) * inv);
    o.w = f2bf((a.w + b.w) * inv);
    *(ushort4*)(ab + (size_t)row * 1024 + d) = o;
}

// ---------------------------------------------------------------------------
extern "C" void kernel_launch(void* const* d_in, const int* in_sizes, int n_in,
                              void* d_out, int out_size, void* d_ws, size_t ws_size,
                              hipStream_t stream) {
    const float* query = (const float*)d_in[0];
    const float* key   = (const float*)d_in[1];
    const float* value = (const float*)d_in[2];
    const void*  mask  = d_in[3];
    const float* Wq = (const float*)d_in[4];
    const float* bq = (const float*)d_in[5];
    const float* Wk = (const float*)d_in[6];
    const float* bk = (const float*)d_in[7];
    const float* Wv = (const float*)d_in[8];
    const float* bv = (const float*)d_in[9];
    const float* Wo = (const float*)d_in[10];
    const float* bo = (const float*)d_in[11];
    float* out = (float*)d_out;

    char* ws = (char*)d_ws;
    const size_t MB = 1024 * 1024;
    // persistent regions
    u64* bits  = (u64*)ws;                             // 512 KB (row-major)
    u64* maskt = (u64*)(ws + 512 * 1024);              // 512 KB (lane-word)
    u16* wob  = (u16*)(ws + 1 * MB);                   // 2 MB
    u16* qb   = (u16*)(ws + 3 * MB);                   // 8 MB (later: ab)
    u16* kb   = (u16*)(ws + 11 * MB);                  // 8 MB
    u16* vbt  = (u16*)(ws + 19 * MB);                  // 8 MB
    // unionA at +27 MB: phase1 = {xq,xk,xv,wqb,wkb,wvb,vtmp} (38 MB),
    //                   phase2 = {Opart 32 MB, lpart 512 KB}
    char* uA = ws + 27 * MB;
    u16* xq   = (u16*)(uA);
    u16* xk   = (u16*)(uA + 8 * MB);
    u16* xv   = (u16*)(uA + 16 * MB);
    u16* wqb  = (u16*)(uA + 24 * MB);
    u16* wkb  = (u16*)(uA + 26 * MB);
    u16* wvb  = (u16*)(uA + 28 * MB);
    u16* vtmp = (u16*)(uA + 30 * MB);
    float* Opart = (float*)(uA);                       // 32 MB (after qkv/vtrans)
    float* lpart = (float*)(uA + 32 * MB);             // 512 KB
    u16* ab = qb;                                      // qb dead after attn

    const size_t NACT = (size_t)MROWS * D_MODEL;       // 4M elements
    const size_t NW   = (size_t)D_MODEL * D_MODEL;     // 1M elements

    CvtJobs j;
    j.src[0] = query; j.dst[0] = xq;  j.n[0] = (int)NACT;
    j.src[1] = key;   j.dst[1] = xk;  j.n[1] = (int)NACT;
    j.src[2] = value; j.dst[2] = xv;  j.n[2] = (int)NACT;
    j.src[3] = Wq;    j.dst[3] = wqb; j.n[3] = (int)NW;
    j.src[4] = Wk;    j.dst[4] = wkb; j.n[4] = (int)NW;
    j.src[5] = Wv;    j.dst[5] = wvb; j.n[5] = (int)NW;
    j.src[6] = Wo;    j.dst[6] = wob; j.n[6] = (int)NW;
    prep_kernel<<<dim3(NACT / 1024, 8), 256, 0, stream>>>(
        j, (const unsigned char*)mask, bits);
    maskt_kernel<<<dim3(64), 256, 0, stream>>>(bits, maskt);

    qkv_gemm_kernel<<<dim3(D_MODEL / 128, MROWS / 128, 3), 256, 0, stream>>>(
        xq, xk, xv, wqb, wkb, wvb, bq, bk, bv, qb, kb, vtmp);
    vtrans_kernel<<<dim3(S_LEN / 64, BATCH * N_HEADS), 256, 0, stream>>>(vtmp, vbt);
    attn_kernel<<<dim3(8, N_HEADS, 4), 512, 0, stream>>>(
        qb, kb, vbt, maskt, Opart, lpart);
    combine_kernel<<<4096, 256, 0, stream>>>(Opart, lpart, ab);
    out_gemm_kernel<<<dim3(D_MODEL / 128, MROWS / 128), 256, 0, stream>>>(
        ab, wob, bo, out);
}